// Round 1
// baseline (901.802 us; speedup 1.0000x reference)
//
#include <hip/hip_runtime.h>
#include <stdint.h>

#define S_LEN 2048
#define EMB   4096
#define NHEAD 32
#define DHEAD 128
#define NBLK  32
#define GDIM  64

typedef float  f32x4  __attribute__((ext_vector_type(4)));
typedef __bf16 bf16x8 __attribute__((ext_vector_type(8)));
typedef unsigned short u16;

__device__ __forceinline__ u16 f2bf(float f) {
  uint32_t u = __float_as_uint(f);
  u += 0x7fffu + ((u >> 16) & 1u);
  return (u16)(u >> 16);
}
__device__ __forceinline__ float bf2f(u16 u) {
  return __uint_as_float(((uint32_t)u) << 16);
}

__device__ __forceinline__ void ld_lds16(const u16* g, u16* l) {
  __builtin_amdgcn_global_load_lds((const __attribute__((address_space(1))) void*)g,
                                   (__attribute__((address_space(3))) void*)l, 16, 0, 0);
}

// fp32 -> bf16 bulk convert (vectorized, n4 = n/4)
__global__ void conv_f32_bf16(const float* __restrict__ in, u16* __restrict__ out, int n4) {
  int i = blockIdx.x * 256 + threadIdx.x;
  if (i >= n4) return;
  float4 v = ((const float4*)in)[i];
  ushort4 o;
  o.x = f2bf(v.x); o.y = f2bf(v.y); o.z = f2bf(v.z); o.w = f2bf(v.w);
  ((ushort4*)out)[i] = o;
}

// C = A(2048x4096) @ B(4096x4096)^T, bf16 in, 128x128 tile, BK=32, 4 waves (32 rows x 128 cols each)
// MODE 0: RoPE epilogue, bf16 out (H,S,D).  MODE 1: bf16 out transposed (H,D,S).  MODE 2: f32 out (S,E).
template<int MODE>
__global__ void __launch_bounds__(256, 2) gemm_bt(
    const u16* __restrict__ A, const u16* __restrict__ B, void* __restrict__ outp,
    const float* __restrict__ cosp, const float* __restrict__ sinp)
{
  __shared__ u16 lA[128 * 32];
  __shared__ u16 lB[128 * 32];
  __shared__ u16 lT[MODE == 1 ? 128 * 136 : 1];

  const int tid = threadIdx.x;
  const int w = tid >> 6, lane = tid & 63;
  const int r = lane & 15, qd = lane >> 4;
  const int m0 = blockIdx.y * 128, n0 = blockIdx.x * 128;
  const int K = EMB;

  f32x4 acc[2][8];
#pragma unroll
  for (int mi = 0; mi < 2; ++mi)
#pragma unroll
    for (int ni = 0; ni < 8; ++ni) acc[mi][ni] = (f32x4){0.f, 0.f, 0.f, 0.f};

  const u16* Ab = A + (size_t)(m0 + w * 16 + (lane >> 2)) * K + (lane & 3) * 8;
  const u16* Bb = B + (size_t)(n0 + w * 16 + (lane >> 2)) * K + (lane & 3) * 8;
  u16* lAb = &lA[(w * 16) * 32];
  u16* lBb = &lB[(w * 16) * 32];

  for (int k0 = 0; k0 < K; k0 += 32) {
    __syncthreads();
    ld_lds16(Ab + k0, lAb);
    ld_lds16(Ab + (size_t)64 * K + k0, lAb + 64 * 32);
    ld_lds16(Bb + k0, lBb);
    ld_lds16(Bb + (size_t)64 * K + k0, lBb + 64 * 32);
    __syncthreads();
    bf16x8 af0 = *(const bf16x8*)&lA[(w * 32 + r) * 32 + qd * 8];
    bf16x8 af1 = *(const bf16x8*)&lA[(w * 32 + 16 + r) * 32 + qd * 8];
#pragma unroll
    for (int ni = 0; ni < 8; ++ni) {
      bf16x8 bf = *(const bf16x8*)&lB[(ni * 16 + r) * 32 + qd * 8];
      acc[0][ni] = __builtin_amdgcn_mfma_f32_16x16x32_bf16(af0, bf, acc[0][ni], 0, 0, 0);
      acc[1][ni] = __builtin_amdgcn_mfma_f32_16x16x32_bf16(af1, bf, acc[1][ni], 0, 0, 0);
    }
  }

  if (MODE == 2) {
    float* out = (float*)outp;
#pragma unroll
    for (int mi = 0; mi < 2; ++mi)
#pragma unroll
      for (int ni = 0; ni < 8; ++ni)
#pragma unroll
        for (int rg = 0; rg < 4; ++rg) {
          int srow = m0 + w * 32 + mi * 16 + qd * 4 + rg;
          out[(size_t)srow * EMB + n0 + ni * 16 + r] = acc[mi][ni][rg];
        }
  } else if (MODE == 0) {
    u16* out = (u16*)outp;
    const int h = n0 >> 7;
#pragma unroll
    for (int mi = 0; mi < 2; ++mi)
#pragma unroll
      for (int ni = 0; ni < 4; ++ni)
#pragma unroll
        for (int rg = 0; rg < 4; ++rg) {
          int srow = m0 + w * 32 + mi * 16 + qd * 4 + rg;
          int dlo = ni * 16 + r;
          float c = cosp[srow * DHEAD + dlo];
          float s = sinp[srow * DHEAD + dlo];
          float lo = acc[mi][ni][rg], hi = acc[mi][ni + 4][rg];
          size_t base = ((size_t)h * S_LEN + srow) * DHEAD;
          out[base + dlo]      = f2bf(lo * c - hi * s);
          out[base + dlo + 64] = f2bf(hi * c + lo * s);
        }
  } else {
    // MODE 1: transpose 128x128 block through LDS, store (H, D, S)
    u16* out = (u16*)outp;
    const int h = n0 >> 7;
#pragma unroll
    for (int mi = 0; mi < 2; ++mi)
#pragma unroll
      for (int ni = 0; ni < 8; ++ni)
#pragma unroll
        for (int rg = 0; rg < 4; ++rg) {
          int sl = w * 32 + mi * 16 + qd * 4 + rg;
          lT[sl * 136 + ni * 16 + r] = f2bf(acc[mi][ni][rg]);
        }
    __syncthreads();
    const int d = tid >> 1, sh = (tid & 1) * 64;
    size_t obase = ((size_t)h * DHEAD + d) * S_LEN + m0 + sh;
#pragma unroll
    for (int i8 = 0; i8 < 8; ++i8) {
      u16 tmp[8];
#pragma unroll
      for (int j = 0; j < 8; ++j) tmp[j] = lT[(sh + i8 * 8 + j) * 136 + d];
      *(uint4*)&out[obase + i8 * 8] = *(uint4*)tmp;
    }
  }
}

// flash attention: one block per (h, qb). q,k: (H,S,D) bf16 (RoPE'd); vt: (H,D,S) bf16.
// ctx out: (S, E) bf16. bmax out: (H, NB, NB) f32 (only kb<=qb written).
__global__ void __launch_bounds__(256, 2) attn_fwd(
    const u16* __restrict__ qg, const u16* __restrict__ kg, const u16* __restrict__ vtg,
    u16* __restrict__ ctx, float* __restrict__ bmax)
{
  __shared__ u16 lK[64 * 136];
  __shared__ u16 lV[128 * 72];
  __shared__ u16 lP[64 * 72];
  __shared__ float lBM[4 * NBLK];

  const int tid = threadIdx.x;
  const int w = tid >> 6, lane = tid & 63;
  const int r = lane & 15, qd = lane >> 4;
  const int qb = blockIdx.x, h = blockIdx.y;

  bf16x8 qf[4];
  {
    const u16* qp = qg + ((size_t)h * S_LEN + qb * 64 + w * 16 + r) * DHEAD + qd * 8;
#pragma unroll
    for (int ki = 0; ki < 4; ++ki) qf[ki] = *(const bf16x8*)(qp + ki * 32);
  }

  f32x4 o[8];
#pragma unroll
  for (int dt = 0; dt < 8; ++dt) o[dt] = (f32x4){0.f, 0.f, 0.f, 0.f};
  float m_run[4], l_run[4];
#pragma unroll
  for (int rg = 0; rg < 4; ++rg) { m_run[rg] = -__builtin_inff(); l_run[rg] = 0.f; }

  const u16* ksrc = kg + (size_t)h * S_LEN * DHEAD;
  const u16* vsrc = vtg + (size_t)h * DHEAD * S_LEN;
  const float scale = 0.08838834764831845f;

  for (int kb = 0; kb <= qb; ++kb) {
    __syncthreads();
#pragma unroll
    for (int i = 0; i < 4; ++i) {
      int c = tid + 256 * i;
      int row = c >> 4, col = (c & 15) * 8;
      *(uint4*)&lK[row * 136 + col] = *(const uint4*)(ksrc + (size_t)(kb * 64 + row) * DHEAD + col);
    }
#pragma unroll
    for (int i = 0; i < 4; ++i) {
      int c = tid + 256 * i;
      int row = c >> 3, col = (c & 7) * 8;
      *(uint4*)&lV[row * 72 + col] = *(const uint4*)(vsrc + (size_t)row * S_LEN + kb * 64 + col);
    }
    __syncthreads();

    f32x4 sf[4];
#pragma unroll
    for (int nt = 0; nt < 4; ++nt) sf[nt] = (f32x4){0.f, 0.f, 0.f, 0.f};
#pragma unroll
    for (int ki = 0; ki < 4; ++ki)
#pragma unroll
      for (int nt = 0; nt < 4; ++nt) {
        bf16x8 bf = *(const bf16x8*)&lK[(nt * 16 + r) * 136 + ki * 32 + qd * 8];
        sf[nt] = __builtin_amdgcn_mfma_f32_16x16x32_bf16(qf[ki], bf, sf[nt], 0, 0, 0);
      }

    float rmax[4];
#pragma unroll
    for (int rg = 0; rg < 4; ++rg) rmax[rg] = -__builtin_inff();
#pragma unroll
    for (int nt = 0; nt < 4; ++nt)
#pragma unroll
      for (int rg = 0; rg < 4; ++rg) {
        float s = sf[nt][rg] * scale;
        if (kb == qb) {
          int col = nt * 16 + r, row = w * 16 + qd * 4 + rg;
          if (col > row) s = -__builtin_inff();
        }
        sf[nt][rg] = s;
        rmax[rg] = fmaxf(rmax[rg], s);
      }
#pragma unroll
    for (int rg = 0; rg < 4; ++rg) {
      float v = rmax[rg];
      v = fmaxf(v, __shfl_xor(v, 1));
      v = fmaxf(v, __shfl_xor(v, 2));
      v = fmaxf(v, __shfl_xor(v, 4));
      v = fmaxf(v, __shfl_xor(v, 8));
      rmax[rg] = v;
    }
    {  // per-wave tile max -> lBM for gate_target block_max
      float v = fmaxf(fmaxf(rmax[0], rmax[1]), fmaxf(rmax[2], rmax[3]));
      v = fmaxf(v, __shfl_xor(v, 16));
      v = fmaxf(v, __shfl_xor(v, 32));
      if (lane == 0) lBM[w * NBLK + kb] = v;
    }

    float alpha[4], rsum[4];
#pragma unroll
    for (int rg = 0; rg < 4; ++rg) {
      float mn = fmaxf(m_run[rg], rmax[rg]);
      alpha[rg] = __expf(m_run[rg] - mn);
      m_run[rg] = mn;
      rsum[rg] = 0.f;
    }
#pragma unroll
    for (int nt = 0; nt < 4; ++nt)
#pragma unroll
      for (int rg = 0; rg < 4; ++rg) {
        float p = __expf(sf[nt][rg] - m_run[rg]);
        sf[nt][rg] = p;
        rsum[rg] += p;
      }
#pragma unroll
    for (int rg = 0; rg < 4; ++rg) {
      float v = rsum[rg];
      v += __shfl_xor(v, 1);
      v += __shfl_xor(v, 2);
      v += __shfl_xor(v, 4);
      v += __shfl_xor(v, 8);
      l_run[rg] = l_run[rg] * alpha[rg] + v;
    }
    // P (C-layout) -> LDS -> A-layout; each wave touches only its own 16 rows
#pragma unroll
    for (int nt = 0; nt < 4; ++nt)
#pragma unroll
      for (int rg = 0; rg < 4; ++rg)
        lP[(w * 16 + qd * 4 + rg) * 72 + nt * 16 + r] = f2bf(sf[nt][rg]);
#pragma unroll
    for (int dt = 0; dt < 8; ++dt)
#pragma unroll
      for (int rg = 0; rg < 4; ++rg) o[dt][rg] *= alpha[rg];
    bf16x8 pa0 = *(const bf16x8*)&lP[(w * 16 + r) * 72 + qd * 8];
    bf16x8 pa1 = *(const bf16x8*)&lP[(w * 16 + r) * 72 + 32 + qd * 8];
#pragma unroll
    for (int dt = 0; dt < 8; ++dt) {
      bf16x8 bv0 = *(const bf16x8*)&lV[(dt * 16 + r) * 72 + qd * 8];
      bf16x8 bv1 = *(const bf16x8*)&lV[(dt * 16 + r) * 72 + 32 + qd * 8];
      o[dt] = __builtin_amdgcn_mfma_f32_16x16x32_bf16(pa0, bv0, o[dt], 0, 0, 0);
      o[dt] = __builtin_amdgcn_mfma_f32_16x16x32_bf16(pa1, bv1, o[dt], 0, 0, 0);
    }
  }

  float inv[4];
#pragma unroll
  for (int rg = 0; rg < 4; ++rg) inv[rg] = 1.f / l_run[rg];
#pragma unroll
  for (int dt = 0; dt < 8; ++dt)
#pragma unroll
    for (int rg = 0; rg < 4; ++rg) {
      int srow = qb * 64 + w * 16 + qd * 4 + rg;
      ctx[(size_t)srow * EMB + h * DHEAD + dt * 16 + r] = f2bf(o[dt][rg] * inv[rg]);
    }
  __syncthreads();
  if (tid <= qb) {
    float v = fmaxf(fmaxf(lBM[0 * NBLK + tid], lBM[1 * NBLK + tid]),
                    fmaxf(lBM[2 * NBLK + tid], lBM[3 * NBLK + tid]));
    bmax[((size_t)h * NBLK + qb) * NBLK + tid] = v;
  }
}

// per-(h,nb) mean over 64 rows of (H,S,D) bf16 -> (H,NB,D) f32
__global__ void bmean(const u16* __restrict__ x, float* __restrict__ out) {
  int nb = blockIdx.x, h = blockIdx.y, d = threadIdx.x;
  const u16* p = x + ((size_t)h * S_LEN + nb * 64) * DHEAD + d;
  float s = 0.f;
#pragma unroll 8
  for (int i = 0; i < 64; ++i) s += bf2f(p[(size_t)i * DHEAD]);
  out[((size_t)h * NBLK + nb) * DHEAD + d] = s * (1.f / 64.f);
}

// gate_pred + gate_target, one block per head
__global__ void __launch_bounds__(256) gate_kernel(
    const float* __restrict__ qm, const float* __restrict__ km,
    const float* __restrict__ Wgq, const float* __restrict__ Wgk,
    const float* __restrict__ bmx, float* __restrict__ gpred, float* __restrict__ gtgt)
{
  __shared__ float gq[NBLK * GDIM], gk[NBLK * GDIM];
  __shared__ float red[256];
  const int h = blockIdx.x, tid = threadIdx.x;

  for (int i = 0; i < 8; ++i) {
    int e = tid + 256 * i;
    int n = e >> 6, g = e & 63;
    const float* qrow = qm + ((size_t)h * NBLK + n) * DHEAD;
    const float* krow = km + ((size_t)h * NBLK + n) * DHEAD;
    const float* wq = Wgq + g * DHEAD;
    const float* wk = Wgk + g * DHEAD;
    float s1 = 0.f, s2 = 0.f;
    for (int d = 0; d < DHEAD; ++d) { s1 += qrow[d] * wq[d]; s2 += krow[d] * wk[d]; }
    gq[e] = s1; gk[e] = s2;
  }
  __syncthreads();

  float gl[4];
  for (int i = 0; i < 4; ++i) {
    int idx = tid + 256 * i;
    int qn = idx >> 5, kn = idx & 31;
    if (kn <= qn) {
      float s = 0.f;
      for (int g = 0; g < GDIM; ++g) s += gq[qn * GDIM + g] * gk[kn * GDIM + g];
      gl[i] = s * 0.125f;
    } else gl[i] = -__builtin_inff();
  }
  float mx = fmaxf(fmaxf(gl[0], gl[1]), fmaxf(gl[2], gl[3]));
  red[tid] = mx; __syncthreads();
  for (int st = 128; st > 0; st >>= 1) { if (tid < st) red[tid] = fmaxf(red[tid], red[tid + st]); __syncthreads(); }
  float gmax = red[0]; __syncthreads();
  float ex[4], lsum = 0.f;
  for (int i = 0; i < 4; ++i) { ex[i] = __expf(gl[i] - gmax); lsum += ex[i]; }
  red[tid] = lsum; __syncthreads();
  for (int st = 128; st > 0; st >>= 1) { if (tid < st) red[tid] += red[tid + st]; __syncthreads(); }
  float invs = 1.f / red[0]; __syncthreads();
  for (int i = 0; i < 4; ++i) gpred[(size_t)h * 1024 + tid + 256 * i] = ex[i] * invs;

  float tl[4];
  for (int i = 0; i < 4; ++i) {
    int idx = tid + 256 * i;
    int qn = idx >> 5, kn = idx & 31;
    tl[i] = (kn <= qn) ? fminf(fmaxf(bmx[(size_t)h * 1024 + idx], -50.f), 50.f) * 0.5f
                       : -__builtin_inff();
  }
  float mx2 = fmaxf(fmaxf(tl[0], tl[1]), fmaxf(tl[2], tl[3]));
  red[tid] = mx2; __syncthreads();
  for (int st = 128; st > 0; st >>= 1) { if (tid < st) red[tid] = fmaxf(red[tid], red[tid + st]); __syncthreads(); }
  float tmax = red[0]; __syncthreads();
  float ex2[4], ls2 = 0.f;
  for (int i = 0; i < 4; ++i) { ex2[i] = __expf(tl[i] - tmax); ls2 += ex2[i]; }
  red[tid] = ls2; __syncthreads();
  for (int st = 128; st > 0; st >>= 1) { if (tid < st) red[tid] += red[tid + st]; __syncthreads(); }
  float inv2 = 1.f / red[0];
  for (int i = 0; i < 4; ++i) gtgt[(size_t)h * 1024 + tid + 256 * i] = ex2[i] * inv2;
}

extern "C" void kernel_launch(void* const* d_in, const int* in_sizes, int n_in,
                              void* d_out, int out_size, void* d_ws, size_t ws_size,
                              hipStream_t stream) {
  const float* hidden = (const float*)d_in[0];
  const float* cosp   = (const float*)d_in[1];
  const float* sinp   = (const float*)d_in[2];
  const float* Wq     = (const float*)d_in[3];
  const float* Wk     = (const float*)d_in[4];
  const float* Wv     = (const float*)d_in[5];
  const float* Wo     = (const float*)d_in[6];
  const float* Wgq    = (const float*)d_in[7];
  const float* Wgk    = (const float*)d_in[8];

  char* ws = (char*)d_ws;
  u16*   wbuf = (u16*)ws;                          // 33,554,432 B (reused for each weight)
  u16*   hid  = (u16*)(ws + 33554432);             // 16,777,216 B
  u16*   qbf  = (u16*)(ws + 50331648);             // 16,777,216 B
  u16*   kbf  = (u16*)(ws + 67108864);             // 16,777,216 B
  u16*   vtb  = (u16*)(ws + 83886080);             // 16,777,216 B
  u16*   ctxb = (u16*)(ws + 100663296);            // 16,777,216 B
  float* bmx  = (float*)(ws + 117440512);          //    131,072 B
  float* qmn  = (float*)(ws + 117571584);          //    524,288 B
  float* kmn  = (float*)(ws + 118095872);          //    524,288 B  (total ~113 MB)

  float* attn_out = (float*)d_out;
  float* gpred = attn_out + (size_t)S_LEN * EMB;   // +8388608
  float* gtgt  = gpred + NHEAD * NBLK * NBLK;      // +32768

  conv_f32_bf16<<<8192, 256, 0, stream>>>(hidden, hid, 2097152);

  conv_f32_bf16<<<16384, 256, 0, stream>>>(Wq, wbuf, 4194304);
  gemm_bt<0><<<dim3(32, 16), 256, 0, stream>>>(hid, wbuf, qbf, cosp, sinp);
  conv_f32_bf16<<<16384, 256, 0, stream>>>(Wk, wbuf, 4194304);
  gemm_bt<0><<<dim3(32, 16), 256, 0, stream>>>(hid, wbuf, kbf, cosp, sinp);
  conv_f32_bf16<<<16384, 256, 0, stream>>>(Wv, wbuf, 4194304);
  gemm_bt<1><<<dim3(32, 16), 256, 0, stream>>>(hid, wbuf, vtb, nullptr, nullptr);

  attn_fwd<<<dim3(NBLK, NHEAD), 256, 0, stream>>>(qbf, kbf, vtb, ctxb, bmx);

  conv_f32_bf16<<<16384, 256, 0, stream>>>(Wo, wbuf, 4194304);
  gemm_bt<2><<<dim3(32, 16), 256, 0, stream>>>(ctxb, wbuf, attn_out, nullptr, nullptr);

  bmean<<<dim3(NBLK, NHEAD), 128, 0, stream>>>(qbf, qmn);
  bmean<<<dim3(NBLK, NHEAD), 128, 0, stream>>>(kbf, kmn);
  gate_kernel<<<NHEAD, 256, 0, stream>>>(qmn, kmn, Wgq, Wgk, bmx, gpred, gtgt);
}

// Round 2
// 790.649 us; speedup vs baseline: 1.1406x; 1.1406x over previous
//
#include <hip/hip_runtime.h>
#include <stdint.h>

#define S_LEN 2048
#define EMB   4096
#define NHEAD 32
#define DHEAD 128
#define NBLK  32
#define GDIM  64

typedef float  f32x4  __attribute__((ext_vector_type(4)));
typedef __bf16 bf16x8 __attribute__((ext_vector_type(8)));
typedef unsigned short u16;

__device__ __forceinline__ u16 f2bf(float f) {
  uint32_t u = __float_as_uint(f);
  u += 0x7fffu + ((u >> 16) & 1u);
  return (u16)(u >> 16);
}
__device__ __forceinline__ float bf2f(u16 u) {
  return __uint_as_float(((uint32_t)u) << 16);
}

__device__ __forceinline__ void ld_lds16(const u16* g, u16* l) {
  __builtin_amdgcn_global_load_lds((const __attribute__((address_space(1))) void*)g,
                                   (__attribute__((address_space(3))) void*)l, 16, 0, 0);
}

// fp32 -> bf16 bulk convert (vectorized, n4 = n/4)
__global__ void conv_f32_bf16(const float* __restrict__ in, u16* __restrict__ out, int n4) {
  int i = blockIdx.x * 256 + threadIdx.x;
  if (i >= n4) return;
  float4 v = ((const float4*)in)[i];
  ushort4 o;
  o.x = f2bf(v.x); o.y = f2bf(v.y); o.z = f2bf(v.z); o.w = f2bf(v.w);
  ((ushort4*)out)[i] = o;
}

// three weights in one dispatch (grid.y selects)
__global__ void conv3_f32_bf16(const float* __restrict__ a, const float* __restrict__ b,
                               const float* __restrict__ c, u16* __restrict__ oa,
                               u16* __restrict__ ob, u16* __restrict__ oc, int n4) {
  int i = blockIdx.x * 256 + threadIdx.x;
  if (i >= n4) return;
  const float* in = (blockIdx.y == 0) ? a : (blockIdx.y == 1) ? b : c;
  u16* out = (blockIdx.y == 0) ? oa : (blockIdx.y == 1) ? ob : oc;
  float4 v = ((const float4*)in)[i];
  ushort4 o;
  o.x = f2bf(v.x); o.y = f2bf(v.y); o.z = f2bf(v.z); o.w = f2bf(v.w);
  ((ushort4*)out)[i] = o;
}

// Fused QKV projection: C = hid(2048x4096) @ W^T for W in {Wq,Wk,Wv}.
// grid (96,16): blockIdx.x 0-31 -> Q (RoPE epilogue), 32-63 -> K (RoPE), 64-95 -> V (transpose to (H,D,S)).
// 128x128 tile, BK=32, 4 waves x (32 rows x 128 cols).
__global__ void __launch_bounds__(256, 2) qkv_gemm(
    const u16* __restrict__ A, const u16* __restrict__ Bq, const u16* __restrict__ Bk,
    const u16* __restrict__ Bv, u16* __restrict__ outq, u16* __restrict__ outk,
    u16* __restrict__ outvt, const float* __restrict__ cosp, const float* __restrict__ sinp)
{
  __shared__ u16 lA[128 * 32];
  __shared__ u16 lB[128 * 32];
  __shared__ u16 lT[128 * 132];

  const int tid = threadIdx.x;
  const int w = tid >> 6, lane = tid & 63;
  const int r = lane & 15, qd = lane >> 4;
  const int nb = blockIdx.x;
  const int which = nb >> 5;          // 0=Q 1=K 2=V
  const int h = nb & 31;              // one head per n-block (DHEAD==128)
  const int m0 = blockIdx.y * 128, n0 = h * 128;
  const int K = EMB;
  const u16* B = (which == 0) ? Bq : (which == 1) ? Bk : Bv;

  f32x4 acc[2][8];
#pragma unroll
  for (int mi = 0; mi < 2; ++mi)
#pragma unroll
    for (int ni = 0; ni < 8; ++ni) acc[mi][ni] = (f32x4){0.f, 0.f, 0.f, 0.f};

  const u16* Ab = A + (size_t)(m0 + w * 16 + (lane >> 2)) * K + (lane & 3) * 8;
  const u16* Bb = B + (size_t)(n0 + w * 16 + (lane >> 2)) * K + (lane & 3) * 8;
  u16* lAb = &lA[(w * 16) * 32];
  u16* lBb = &lB[(w * 16) * 32];

  for (int k0 = 0; k0 < K; k0 += 32) {
    __syncthreads();
    ld_lds16(Ab + k0, lAb);
    ld_lds16(Ab + (size_t)64 * K + k0, lAb + 64 * 32);
    ld_lds16(Bb + k0, lBb);
    ld_lds16(Bb + (size_t)64 * K + k0, lBb + 64 * 32);
    __syncthreads();
    bf16x8 af0 = *(const bf16x8*)&lA[(w * 32 + r) * 32 + qd * 8];
    bf16x8 af1 = *(const bf16x8*)&lA[(w * 32 + 16 + r) * 32 + qd * 8];
#pragma unroll
    for (int ni = 0; ni < 8; ++ni) {
      bf16x8 bf = *(const bf16x8*)&lB[(ni * 16 + r) * 32 + qd * 8];
      acc[0][ni] = __builtin_amdgcn_mfma_f32_16x16x32_bf16(af0, bf, acc[0][ni], 0, 0, 0);
      acc[1][ni] = __builtin_amdgcn_mfma_f32_16x16x32_bf16(af1, bf, acc[1][ni], 0, 0, 0);
    }
  }

  if (which < 2) {
    u16* out = which ? outk : outq;
#pragma unroll
    for (int mi = 0; mi < 2; ++mi)
#pragma unroll
      for (int ni = 0; ni < 4; ++ni)
#pragma unroll
        for (int rg = 0; rg < 4; ++rg) {
          int srow = m0 + w * 32 + mi * 16 + qd * 4 + rg;
          int dlo = ni * 16 + r;
          float c = cosp[srow * DHEAD + dlo];
          float s = sinp[srow * DHEAD + dlo];
          float lo = acc[mi][ni][rg], hi = acc[mi][ni + 4][rg];
          size_t base = ((size_t)h * S_LEN + srow) * DHEAD;
          out[base + dlo]      = f2bf(lo * c - hi * s);
          out[base + dlo + 64] = f2bf(hi * c + lo * s);
        }
  } else {
    // V: transpose 128x128 block through LDS, store (H, D, S)
#pragma unroll
    for (int mi = 0; mi < 2; ++mi)
#pragma unroll
      for (int ni = 0; ni < 8; ++ni)
#pragma unroll
        for (int rg = 0; rg < 4; ++rg) {
          int sl = w * 32 + mi * 16 + qd * 4 + rg;
          lT[sl * 132 + ni * 16 + r] = f2bf(acc[mi][ni][rg]);
        }
    __syncthreads();
    const int d = tid >> 1, sh = (tid & 1) * 64;
    size_t obase = ((size_t)h * DHEAD + d) * S_LEN + m0 + sh;
#pragma unroll
    for (int i8 = 0; i8 < 8; ++i8) {
      u16 tmp[8];
#pragma unroll
      for (int j = 0; j < 8; ++j) tmp[j] = lT[(sh + i8 * 8 + j) * 132 + d];
      *(uint4*)&outvt[obase + i8 * 8] = *(uint4*)tmp;
    }
  }
}

// Output projection: C(2048x4096) = ctx @ Wo^T, f32 out.
__global__ void __launch_bounds__(256, 2) gemm_out(
    const u16* __restrict__ A, const u16* __restrict__ B, float* __restrict__ out)
{
  __shared__ u16 lA[128 * 32];
  __shared__ u16 lB[128 * 32];
  const int tid = threadIdx.x;
  const int w = tid >> 6, lane = tid & 63;
  const int r = lane & 15, qd = lane >> 4;
  const int m0 = blockIdx.y * 128, n0 = blockIdx.x * 128;
  const int K = EMB;

  f32x4 acc[2][8];
#pragma unroll
  for (int mi = 0; mi < 2; ++mi)
#pragma unroll
    for (int ni = 0; ni < 8; ++ni) acc[mi][ni] = (f32x4){0.f, 0.f, 0.f, 0.f};

  const u16* Ab = A + (size_t)(m0 + w * 16 + (lane >> 2)) * K + (lane & 3) * 8;
  const u16* Bb = B + (size_t)(n0 + w * 16 + (lane >> 2)) * K + (lane & 3) * 8;
  u16* lAb = &lA[(w * 16) * 32];
  u16* lBb = &lB[(w * 16) * 32];

  for (int k0 = 0; k0 < K; k0 += 32) {
    __syncthreads();
    ld_lds16(Ab + k0, lAb);
    ld_lds16(Ab + (size_t)64 * K + k0, lAb + 64 * 32);
    ld_lds16(Bb + k0, lBb);
    ld_lds16(Bb + (size_t)64 * K + k0, lBb + 64 * 32);
    __syncthreads();
    bf16x8 af0 = *(const bf16x8*)&lA[(w * 32 + r) * 32 + qd * 8];
    bf16x8 af1 = *(const bf16x8*)&lA[(w * 32 + 16 + r) * 32 + qd * 8];
#pragma unroll
    for (int ni = 0; ni < 8; ++ni) {
      bf16x8 bf = *(const bf16x8*)&lB[(ni * 16 + r) * 32 + qd * 8];
      acc[0][ni] = __builtin_amdgcn_mfma_f32_16x16x32_bf16(af0, bf, acc[0][ni], 0, 0, 0);
      acc[1][ni] = __builtin_amdgcn_mfma_f32_16x16x32_bf16(af1, bf, acc[1][ni], 0, 0, 0);
    }
  }
#pragma unroll
  for (int mi = 0; mi < 2; ++mi)
#pragma unroll
    for (int ni = 0; ni < 8; ++ni)
#pragma unroll
      for (int rg = 0; rg < 4; ++rg) {
        int srow = m0 + w * 32 + mi * 16 + qd * 4 + rg;
        out[(size_t)srow * EMB + n0 + ni * 16 + r] = acc[mi][ni][rg];
      }
}

// flash attention, load-balanced: block (blockIdx.x in [0,16)) processes q-blocks
// qb = blockIdx.x and 31-blockIdx.x  => exactly 33 K-tiles per block.
__global__ void __launch_bounds__(256, 2) attn_fwd(
    const u16* __restrict__ qg, const u16* __restrict__ kg, const u16* __restrict__ vtg,
    u16* __restrict__ ctx, float* __restrict__ bmax)
{
  __shared__ u16 lK[64 * 132];
  __shared__ u16 lV[128 * 76];
  __shared__ u16 lP[64 * 76];
  __shared__ float lBM[4 * NBLK];

  const int tid = threadIdx.x;
  const int w = tid >> 6, lane = tid & 63;
  const int r = lane & 15, qd = lane >> 4;
  const int h = blockIdx.y;
  const u16* ksrc = kg + (size_t)h * S_LEN * DHEAD;
  const u16* vsrc = vtg + (size_t)h * DHEAD * S_LEN;
  const float scale = 0.08838834764831845f;

  for (int qsel = 0; qsel < 2; ++qsel) {
    const int qb = qsel ? (31 - (int)blockIdx.x) : (int)blockIdx.x;

    bf16x8 qf[4];
    {
      const u16* qp = qg + ((size_t)h * S_LEN + qb * 64 + w * 16 + r) * DHEAD + qd * 8;
#pragma unroll
      for (int ki = 0; ki < 4; ++ki) qf[ki] = *(const bf16x8*)(qp + ki * 32);
    }

    f32x4 o[8];
#pragma unroll
    for (int dt = 0; dt < 8; ++dt) o[dt] = (f32x4){0.f, 0.f, 0.f, 0.f};
    float m_run[4], l_run[4];
#pragma unroll
    for (int rg = 0; rg < 4; ++rg) { m_run[rg] = -__builtin_inff(); l_run[rg] = 0.f; }

    for (int kb = 0; kb <= qb; ++kb) {
      __syncthreads();
#pragma unroll
      for (int i = 0; i < 4; ++i) {
        int c = tid + 256 * i;
        int row = c >> 4, col = (c & 15) * 8;
        *(uint4*)&lK[row * 132 + col] = *(const uint4*)(ksrc + (size_t)(kb * 64 + row) * DHEAD + col);
      }
#pragma unroll
      for (int i = 0; i < 4; ++i) {
        int c = tid + 256 * i;
        int row = c >> 3, col = (c & 7) * 8;
        *(uint4*)&lV[row * 76 + col] = *(const uint4*)(vsrc + (size_t)row * S_LEN + kb * 64 + col);
      }
      __syncthreads();

      f32x4 sf[4];
#pragma unroll
      for (int nt = 0; nt < 4; ++nt) sf[nt] = (f32x4){0.f, 0.f, 0.f, 0.f};
#pragma unroll
      for (int ki = 0; ki < 4; ++ki)
#pragma unroll
        for (int nt = 0; nt < 4; ++nt) {
          bf16x8 bf = *(const bf16x8*)&lK[(nt * 16 + r) * 132 + ki * 32 + qd * 8];
          sf[nt] = __builtin_amdgcn_mfma_f32_16x16x32_bf16(qf[ki], bf, sf[nt], 0, 0, 0);
        }

      float rmax[4];
#pragma unroll
      for (int rg = 0; rg < 4; ++rg) rmax[rg] = -__builtin_inff();
#pragma unroll
      for (int nt = 0; nt < 4; ++nt)
#pragma unroll
        for (int rg = 0; rg < 4; ++rg) {
          float s = sf[nt][rg] * scale;
          if (kb == qb) {
            int col = nt * 16 + r, row = w * 16 + qd * 4 + rg;
            if (col > row) s = -__builtin_inff();
          }
          sf[nt][rg] = s;
          rmax[rg] = fmaxf(rmax[rg], s);
        }
#pragma unroll
      for (int rg = 0; rg < 4; ++rg) {
        float v = rmax[rg];
        v = fmaxf(v, __shfl_xor(v, 1));
        v = fmaxf(v, __shfl_xor(v, 2));
        v = fmaxf(v, __shfl_xor(v, 4));
        v = fmaxf(v, __shfl_xor(v, 8));
        rmax[rg] = v;
      }
      {  // per-wave tile max -> lBM for gate_target block_max
        float v = fmaxf(fmaxf(rmax[0], rmax[1]), fmaxf(rmax[2], rmax[3]));
        v = fmaxf(v, __shfl_xor(v, 16));
        v = fmaxf(v, __shfl_xor(v, 32));
        if (lane == 0) lBM[w * NBLK + kb] = v;
      }

      float alpha[4], rsum[4];
#pragma unroll
      for (int rg = 0; rg < 4; ++rg) {
        float mn = fmaxf(m_run[rg], rmax[rg]);
        alpha[rg] = __expf(m_run[rg] - mn);
        m_run[rg] = mn;
        rsum[rg] = 0.f;
      }
#pragma unroll
      for (int nt = 0; nt < 4; ++nt)
#pragma unroll
        for (int rg = 0; rg < 4; ++rg) {
          float p = __expf(sf[nt][rg] - m_run[rg]);
          sf[nt][rg] = p;
          rsum[rg] += p;
        }
#pragma unroll
      for (int rg = 0; rg < 4; ++rg) {
        float v = rsum[rg];
        v += __shfl_xor(v, 1);
        v += __shfl_xor(v, 2);
        v += __shfl_xor(v, 4);
        v += __shfl_xor(v, 8);
        l_run[rg] = l_run[rg] * alpha[rg] + v;
      }
      // P (C-layout) -> LDS -> A-layout; each wave touches only its own 16 rows
#pragma unroll
      for (int nt = 0; nt < 4; ++nt)
#pragma unroll
        for (int rg = 0; rg < 4; ++rg)
          lP[(w * 16 + qd * 4 + rg) * 76 + nt * 16 + r] = f2bf(sf[nt][rg]);
#pragma unroll
      for (int dt = 0; dt < 8; ++dt)
#pragma unroll
        for (int rg = 0; rg < 4; ++rg) o[dt][rg] *= alpha[rg];
      bf16x8 pa0 = *(const bf16x8*)&lP[(w * 16 + r) * 76 + qd * 8];
      bf16x8 pa1 = *(const bf16x8*)&lP[(w * 16 + r) * 76 + 32 + qd * 8];
#pragma unroll
      for (int dt = 0; dt < 8; ++dt) {
        bf16x8 bv0 = *(const bf16x8*)&lV[(dt * 16 + r) * 76 + qd * 8];
        bf16x8 bv1 = *(const bf16x8*)&lV[(dt * 16 + r) * 76 + 32 + qd * 8];
        o[dt] = __builtin_amdgcn_mfma_f32_16x16x32_bf16(pa0, bv0, o[dt], 0, 0, 0);
        o[dt] = __builtin_amdgcn_mfma_f32_16x16x32_bf16(pa1, bv1, o[dt], 0, 0, 0);
      }
    }

    float inv[4];
#pragma unroll
    for (int rg = 0; rg < 4; ++rg) inv[rg] = 1.f / l_run[rg];
#pragma unroll
    for (int dt = 0; dt < 8; ++dt)
#pragma unroll
      for (int rg = 0; rg < 4; ++rg) {
        int srow = qb * 64 + w * 16 + qd * 4 + rg;
        ctx[(size_t)srow * EMB + h * DHEAD + dt * 16 + r] = f2bf(o[dt][rg] * inv[rg]);
      }
    __syncthreads();
    if (tid <= qb) {
      float v = fmaxf(fmaxf(lBM[0 * NBLK + tid], lBM[1 * NBLK + tid]),
                      fmaxf(lBM[2 * NBLK + tid], lBM[3 * NBLK + tid]));
      bmax[((size_t)h * NBLK + qb) * NBLK + tid] = v;
    }
  }
}

// per-(h,nb) mean over 64 rows, q and k in one dispatch (grid.z selects). 128 thr, u32 loads.
__global__ void bmean2(const u16* __restrict__ q, const u16* __restrict__ k,
                       float* __restrict__ qo, float* __restrict__ ko) {
  int nb = blockIdx.x, h = blockIdx.y, t = threadIdx.x;
  const u16* x = blockIdx.z ? k : q;
  float* out = blockIdx.z ? ko : qo;
  const u16* p = x + ((size_t)h * S_LEN + nb * 64) * DHEAD + t * 2;
  float s0 = 0.f, s1 = 0.f;
#pragma unroll 8
  for (int i = 0; i < 64; ++i) {
    uint32_t v = *(const uint32_t*)(p + (size_t)i * DHEAD);
    s0 += bf2f((u16)v);
    s1 += bf2f((u16)(v >> 16));
  }
  float2 rr = {s0 * (1.f / 64.f), s1 * (1.f / 64.f)};
  *(float2*)&out[((size_t)h * NBLK + nb) * DHEAD + t * 2] = rr;
}

// gate_pred + gate_target, one block per head
__global__ void __launch_bounds__(256) gate_kernel(
    const float* __restrict__ qm, const float* __restrict__ km,
    const float* __restrict__ Wgq, const float* __restrict__ Wgk,
    const float* __restrict__ bmx, float* __restrict__ gpred, float* __restrict__ gtgt)
{
  __shared__ float gq[NBLK * GDIM], gk[NBLK * GDIM];
  __shared__ float red[256];
  const int h = blockIdx.x, tid = threadIdx.x;

  for (int i = 0; i < 8; ++i) {
    int e = tid + 256 * i;
    int n = e >> 6, g = e & 63;
    const float* qrow = qm + ((size_t)h * NBLK + n) * DHEAD;
    const float* krow = km + ((size_t)h * NBLK + n) * DHEAD;
    const float* wq = Wgq + g * DHEAD;
    const float* wk = Wgk + g * DHEAD;
    float s1 = 0.f, s2 = 0.f;
    for (int d = 0; d < DHEAD; ++d) { s1 += qrow[d] * wq[d]; s2 += krow[d] * wk[d]; }
    gq[e] = s1; gk[e] = s2;
  }
  __syncthreads();

  float gl[4];
  for (int i = 0; i < 4; ++i) {
    int idx = tid + 256 * i;
    int qn = idx >> 5, kn = idx & 31;
    if (kn <= qn) {
      float s = 0.f;
      for (int g = 0; g < GDIM; ++g) s += gq[qn * GDIM + g] * gk[kn * GDIM + g];
      gl[i] = s * 0.125f;
    } else gl[i] = -__builtin_inff();
  }
  float mx = fmaxf(fmaxf(gl[0], gl[1]), fmaxf(gl[2], gl[3]));
  red[tid] = mx; __syncthreads();
  for (int st = 128; st > 0; st >>= 1) { if (tid < st) red[tid] = fmaxf(red[tid], red[tid + st]); __syncthreads(); }
  float gmax = red[0]; __syncthreads();
  float ex[4], lsum = 0.f;
  for (int i = 0; i < 4; ++i) { ex[i] = __expf(gl[i] - gmax); lsum += ex[i]; }
  red[tid] = lsum; __syncthreads();
  for (int st = 128; st > 0; st >>= 1) { if (tid < st) red[tid] += red[tid + st]; __syncthreads(); }
  float invs = 1.f / red[0]; __syncthreads();
  for (int i = 0; i < 4; ++i) gpred[(size_t)h * 1024 + tid + 256 * i] = ex[i] * invs;

  float tl[4];
  for (int i = 0; i < 4; ++i) {
    int idx = tid + 256 * i;
    int qn = idx >> 5, kn = idx & 31;
    tl[i] = (kn <= qn) ? fminf(fmaxf(bmx[(size_t)h * 1024 + idx], -50.f), 50.f) * 0.5f
                       : -__builtin_inff();
  }
  float mx2 = fmaxf(fmaxf(tl[0], tl[1]), fmaxf(tl[2], tl[3]));
  red[tid] = mx2; __syncthreads();
  for (int st = 128; st > 0; st >>= 1) { if (tid < st) red[tid] = fmaxf(red[tid], red[tid + st]); __syncthreads(); }
  float tmax = red[0]; __syncthreads();
  float ex2[4], ls2 = 0.f;
  for (int i = 0; i < 4; ++i) { ex2[i] = __expf(tl[i] - tmax); ls2 += ex2[i]; }
  red[tid] = ls2; __syncthreads();
  for (int st = 128; st > 0; st >>= 1) { if (tid < st) red[tid] += red[tid + st]; __syncthreads(); }
  float inv2 = 1.f / red[0];
  for (int i = 0; i < 4; ++i) gtgt[(size_t)h * 1024 + tid + 256 * i] = ex2[i] * inv2;
}

extern "C" void kernel_launch(void* const* d_in, const int* in_sizes, int n_in,
                              void* d_out, int out_size, void* d_ws, size_t ws_size,
                              hipStream_t stream) {
  const float* hidden = (const float*)d_in[0];
  const float* cosp   = (const float*)d_in[1];
  const float* sinp   = (const float*)d_in[2];
  const float* Wq     = (const float*)d_in[3];
  const float* Wk     = (const float*)d_in[4];
  const float* Wv     = (const float*)d_in[5];
  const float* Wo     = (const float*)d_in[6];
  const float* Wgq    = (const float*)d_in[7];
  const float* Wgk    = (const float*)d_in[8];

  char* ws = (char*)d_ws;
  // ws layout (total exactly 128 MiB):
  u16* wqb = (u16*)ws;                         // 33,554,432 B (Wq bf16; later Wo bf16)
  u16* wkb = (u16*)(ws + 33554432);            // 33,554,432 B (Wk bf16; later bmx/qmn/kmn)
  u16* hid = (u16*)(ws + 67108864);            // 16,777,216 B (hidden bf16; later ctx)
  u16* qbf = (u16*)(ws + 83886080);            // 16,777,216 B
  u16* kbf = (u16*)(ws + 100663296);           // 16,777,216 B
  u16* vtb = (u16*)(ws + 117440512);           // 16,777,216 B  -> end 134,217,728
  // aliases (regions free after qkv_gemm):
  float* bmx = (float*)(ws + 33554432);        // 131,072 B
  float* qmn = (float*)(ws + 33554432 + 131072);
  float* kmn = (float*)(ws + 33554432 + 655360);
  u16* ctx = hid;                              // hid dead after qkv_gemm
  u16* wvb = (u16*)d_out;                      // Wv bf16 staged in d_out scratch (33.5 MB);
                                               // overwritten by gemm_out at the end.

  float* attn_out = (float*)d_out;
  float* gpred = attn_out + (size_t)S_LEN * EMB;
  float* gtgt  = gpred + NHEAD * NBLK * NBLK;

  conv3_f32_bf16<<<dim3(16384, 3), 256, 0, stream>>>(Wq, Wk, Wv, wqb, wkb, wvb, 4194304);
  conv_f32_bf16<<<8192, 256, 0, stream>>>(hidden, hid, 2097152);

  qkv_gemm<<<dim3(96, 16), 256, 0, stream>>>(hid, wqb, wkb, wvb, qbf, kbf, vtb, cosp, sinp);

  conv_f32_bf16<<<16384, 256, 0, stream>>>(Wo, wqb, 4194304);  // wqb free after qkv_gemm

  attn_fwd<<<dim3(16, NHEAD), 256, 0, stream>>>(qbf, kbf, vtb, ctx, bmx);

  bmean2<<<dim3(NBLK, NHEAD, 2), 128, 0, stream>>>(qbf, kbf, qmn, kmn);
  gate_kernel<<<NHEAD, 256, 0, stream>>>(qmn, kmn, Wgq, Wgk, bmx, gpred, gtgt);

  gemm_out<<<dim3(32, 16), 256, 0, stream>>>(ctx, wqb, attn_out);
}